// Round 14
// baseline (4111.618 us; speedup 1.0000x reference)
//
#include <hip/hip_runtime.h>
#include <hip/hip_bf16.h>

// AUGRU dynamic RNN: B=1024, T=512, D=128.
// Round-14: TRUE TLP=4 with phase shift. 32 blocks x 1024 threads (16
// waves): waves 0-7 = batch group A (16 rows), waves 8-15 = group B (next
// 16). Each SIMD hosts 2 A-waves + 2 B-waves. Group B runs HALF A STEP
// behind, so each barrier interval = {A's H1: gate MFMAs + x-partials +
// act} || {B's H2: cand MFMA + update + stage} -> heterogeneous phases
// co-resident per SIMD (MFMA per interval balanced 20+4). Per-wave stream,
// math, LDS pattern byte-identical to R9 (525.8us best): R5 cross-step
// x-partials, column-aligned gates + register h, cvt_pk_bf16, folded
// biases, lgkm-only barriers. Unlike R7 (ILP-serialized both groups in one
// wave, spilled), groups here are in DIFFERENT waves -> scheduler overlap.
// __launch_bounds__(1024) single-arg: compiler must fit 4 waves/SIMD
// (<=128 VGPR; R9 uses 112). R11's (1024,4) bug gave 64 VGPR -> spills.

#define Bn 1024
#define Tn 512
#define Dn 128

typedef __attribute__((ext_vector_type(8))) short short8;   // 8 bf16 (4 VGPR)
typedef __attribute__((ext_vector_type(4))) float f32x4;

#define BS 136   // bf16 LDS row stride (shorts): 272 B = 17*16B

#define NL2E  (-1.4426950408889634f)   // -log2(e)
#define N2L2E (-2.8853900817779268f)   // -2*log2(e)

__device__ __forceinline__ short f2bf(float f) {            // cold paths only
    __hip_bfloat16 h = __float2bfloat16(f);   // RNE
    return __builtin_bit_cast(short, h);
}
__device__ __forceinline__ unsigned cvt_pk_bf16(float a, float b) {
    unsigned r;
    asm("v_cvt_pk_bf16_f32 %0, %1, %2" : "=v"(r) : "v"(a), "v"(b));
    return r;
}
// LDS-only barrier: order LDS ops across waves WITHOUT draining vmcnt.
__device__ __forceinline__ void barrier_lds() {
    __builtin_amdgcn_sched_barrier(0);
    asm volatile("s_waitcnt lgkmcnt(0)" ::: "memory");
    __builtin_amdgcn_s_barrier();
    __builtin_amdgcn_sched_barrier(0);
}

#define MFMA_(a, b, c) __builtin_amdgcn_mfma_f32_16x16x32_bf16((a), (b), (c), 0, 0, 0)

__launch_bounds__(1024)
__global__ void augru_kernel(const float* __restrict__ X,    // [B,T,D]
                             const float* __restrict__ ATT,  // [B,T,1]
                             const float* __restrict__ GK,   // [256,256]
                             const float* __restrict__ GB,   // [256]
                             const float* __restrict__ CK,   // [256,128]
                             const float* __restrict__ CB,   // [128]
                             const int*   __restrict__ SL,   // [B,1]
                             float* __restrict__ OUT) {      // [B,T,D]
    __shared__ short hb [2][16 * BS];      // [group] h bf16 mirror
    __shared__ short rhb[2][16 * BS];      // [group] r*h bf16
    __shared__ short xb [2][2][16 * BS];   // [group][slot]; slot s&1 = x(s)
    __shared__ float abuf[2][2][16];       // [group][slot] raw a
    __shared__ int   lenbuf[2][16];

    const int tid  = threadIdx.x;
    const int g    = tid >> 9;          // group 0 (A) / 1 (B)
    const int gt   = tid & 511;         // id within group
    const int wid  = gt >> 6;           // 0..7 column-wave in group
    const int lane = tid & 63;
    const int lm   = lane & 15;
    const int q    = lane >> 4;
    const int b0   = blockIdx.x * 32 + 16 * g;
    const int ccol = 16 * wid + lm;     // wave's owned column

    // ---------- preload weight B-frags (B[k][n]: n=lane&15, k=q*8+j) ----------
    short8 fgx0[4], fgx1[4], fgh0[4], fgh1[4], fcx[4], fch[4];
#pragma unroll
    for (int ks = 0; ks < 4; ++ks) {
        short8 v0, v1, v2, v3, v4, v5;
#pragma unroll
        for (int j = 0; j < 8; ++j) {
            const int k = ks * 32 + q * 8 + j;
            v0[j] = f2bf(GK[k * 256 + ccol]);               // x-part, r col
            v1[j] = f2bf(GK[k * 256 + 128 + ccol]);         // x-part, u col
            v2[j] = f2bf(GK[(128 + k) * 256 + ccol]);       // h-part, r col
            v3[j] = f2bf(GK[(128 + k) * 256 + 128 + ccol]); // h-part, u col
            v4[j] = f2bf(CK[k * 128 + ccol]);               // cand x-part
            v5[j] = f2bf(CK[(128 + k) * 128 + ccol]);       // cand rh-part
        }
        fgx0[ks] = v0; fgx1[ks] = v1; fgh0[ks] = v2; fgh1[ks] = v3;
        fcx[ks] = v4;  fch[ks] = v5;
    }
    const float pb0 = GB[ccol]       * NL2E;
    const float pb1 = GB[128 + ccol] * NL2E;
    const float cbp = CB[ccol]       * N2L2E;

    // ---------- init LDS (each group its own arrays) ----------
    for (int i = gt; i < 16 * BS; i += 512) hb[g][i] = 0;
    if (gt < 16) {
        lenbuf[g][gt]  = SL[b0 + gt];
        abuf[g][0][gt] = ATT[(size_t)(b0 + gt) * Tn];
    }
    const int prow = gt >> 5;             // x staging: row 0..15
    const int pcol = (gt & 31) * 4;       // 4 consecutive floats
    {   // stage x(0) into xb[g][0]
        float4 v = *(const float4*)(X + ((size_t)(b0 + prow) * Tn + 0) * Dn + pcol);
        uint2 pp; pp.x = cvt_pk_bf16(v.x, v.y); pp.y = cvt_pk_bf16(v.z, v.w);
        *(uint2*)&xb[g][0][prow * BS + pcol] = pp;
    }
    __syncthreads();

    int len_i[4];
    float h_reg[4] = {0.f, 0.f, 0.f, 0.f};   // master h: rows q*4+i, col ccol
#pragma unroll
    for (int i = 0; i < 4; ++i) len_i[i] = lenbuf[g][q * 4 + i];

    // ---------- prologue: x-partials (set A) for step 0; stage x(1) ----------
    f32x4 pg0A = {0,0,0,0}, pg1A = {0,0,0,0}, pcA = {0,0,0,0};
    f32x4 pg0B, pg1B, pcB;
    {
        short8 ax0[4];
#pragma unroll
        for (int ks = 0; ks < 4; ++ks)
            ax0[ks] = *(const short8*)&xb[g][0][lm * BS + ks * 32 + q * 8];
#pragma unroll
        for (int ks = 0; ks < 4; ++ks) {
            pg0A = MFMA_(ax0[ks], fgx0[ks], pg0A);
            pg1A = MFMA_(ax0[ks], fgx1[ks], pg1A);
            pcA  = MFMA_(ax0[ks], fcx[ks],  pcA);
        }
        float4 v = *(const float4*)(X + ((size_t)(b0 + prow) * Tn + 1) * Dn + pcol);
        uint2 pp; pp.x = cvt_pk_bf16(v.x, v.y); pp.y = cvt_pk_bf16(v.z, v.w);
        *(uint2*)&xb[g][1][prow * BS + pcol] = pp;
    }
    __syncthreads();

    // state carried across barriers (per wave)
    float4 xpre; float apre; float up[4];

    // H1(t): gate h-MFMAs + x-partial MFMAs + act + rhb write.
    // Consumes gate partials PIN0/PIN1 (set holding step-t partials);
    // produces full next set (POUT0, POUT1, POUTC).
#define H1(t, PIN0, PIN1, POUT0, POUT1, POUTC)                                    \
    {                                                                             \
        const int tp1 = ((t) + 1 < Tn) ? (t) + 1 : Tn - 1;                        \
        const int tp2 = ((t) + 2 < Tn) ? (t) + 2 : Tn - 1;                        \
        xpre = *(const float4*)(X + ((size_t)(b0 + prow) * Tn + tp2) * Dn + pcol); \
        apre = (gt < 16) ? ATT[(size_t)(b0 + gt) * Tn + tp1] : 0.0f;              \
        short8 axn[4], ah[4];                                                     \
        _Pragma("unroll")                                                         \
        for (int ks = 0; ks < 4; ++ks) {                                          \
            axn[ks] = *(const short8*)&xb[g][((t) + 1) & 1][lm * BS + ks * 32 + q * 8]; \
            ah[ks]  = *(const short8*)&hb[g][lm * BS + ks * 32 + q * 8];          \
        }                                                                         \
        f32x4 g0 = PIN0, g1 = PIN1;                                               \
        f32x4 n0 = {0,0,0,0}, n1 = {0,0,0,0}, n2 = {0,0,0,0};                     \
        _Pragma("unroll")                                                         \
        for (int ks = 0; ks < 4; ++ks) {                                          \
            g0 = MFMA_(ah[ks], fgh0[ks], g0);                                     \
            g1 = MFMA_(ah[ks], fgh1[ks], g1);                                     \
        }                                                                         \
        _Pragma("unroll")                                                         \
        for (int ks = 0; ks < 4; ++ks) {                                          \
            n0 = MFMA_(axn[ks], fgx0[ks], n0);                                    \
            n1 = MFMA_(axn[ks], fgx1[ks], n1);                                    \
            n2 = MFMA_(axn[ks], fcx[ks],  n2);                                    \
        }                                                                         \
        float am[4], rhv[4];                                                      \
        _Pragma("unroll")                                                         \
        for (int i = 0; i < 4; ++i) am[i] = 1.0f - abuf[g][(t) & 1][q * 4 + i];   \
        _Pragma("unroll")                                                         \
        for (int i = 0; i < 4; ++i) {                                             \
            const float e0 = __builtin_amdgcn_exp2f(fmaf(g0[i], NL2E, pb0));      \
            rhv[i] = __builtin_amdgcn_rcpf(1.0f + e0) * h_reg[i];                 \
            const float e1 = __builtin_amdgcn_exp2f(fmaf(g1[i], NL2E, pb1));      \
            up[i] = am[i] * __builtin_amdgcn_rcpf(1.0f + e1);                     \
        }                                                                         \
        {                                                                         \
            const unsigned pA_ = cvt_pk_bf16(rhv[0], rhv[1]);                     \
            const unsigned pB_ = cvt_pk_bf16(rhv[2], rhv[3]);                     \
            rhb[g][(q * 4 + 0) * BS + ccol] = (short)pA_;                         \
            rhb[g][(q * 4 + 1) * BS + ccol] = (short)(pA_ >> 16);                 \
            rhb[g][(q * 4 + 2) * BS + ccol] = (short)pB_;                         \
            rhb[g][(q * 4 + 3) * BS + ccol] = (short)(pB_ >> 16);                 \
        }                                                                         \
        POUT0 = n0; POUT1 = n1; POUTC = n2;                                       \
    }

    // H2(t): cand MFMA chain + h update + OUT + hb write + stage x/a.
    // Consumes cand partial PINC (same set H1(t) read) and up[]/xpre/apre.
#define H2(t, PINC)                                                               \
    {                                                                             \
        short8 arh[4];                                                            \
        _Pragma("unroll")                                                         \
        for (int ks = 0; ks < 4; ++ks)                                            \
            arh[ks] = *(const short8*)&rhb[g][lm * BS + ks * 32 + q * 8];         \
        f32x4 cc = PINC;                                                          \
        _Pragma("unroll")                                                         \
        for (int ks = 0; ks < 4; ++ks)                                            \
            cc = MFMA_(arh[ks], fch[ks], cc);                                     \
        float hxv[4];                                                             \
        _Pragma("unroll")                                                         \
        for (int i = 0; i < 4; ++i) {                                             \
            const int row = q * 4 + i;                                            \
            const float e  = __builtin_amdgcn_exp2f(fmaf(cc[i], N2L2E, cbp));     \
            const float cv = fmaf(2.0f, __builtin_amdgcn_rcpf(1.0f + e), -1.0f);  \
            const float hn = fmaf(up[i], h_reg[i] - cv, cv);                      \
            const bool valid = ((t) < len_i[i]);                                  \
            const float hnext = valid ? hn : h_reg[i];                            \
            OUT[((size_t)(b0 + row) * Tn + (t)) * Dn + ccol] = valid ? hn : 0.0f; \
            h_reg[i] = hnext;                                                     \
            hxv[i] = hnext;                                                       \
        }                                                                         \
        {                                                                         \
            const unsigned pA_ = cvt_pk_bf16(hxv[0], hxv[1]);                     \
            const unsigned pB_ = cvt_pk_bf16(hxv[2], hxv[3]);                     \
            hb[g][(q * 4 + 0) * BS + ccol] = (short)pA_;                          \
            hb[g][(q * 4 + 1) * BS + ccol] = (short)(pA_ >> 16);                  \
            hb[g][(q * 4 + 2) * BS + ccol] = (short)pB_;                          \
            hb[g][(q * 4 + 3) * BS + ccol] = (short)(pB_ >> 16);                  \
        }                                                                         \
        {                                                                         \
            uint2 pp_;                                                            \
            pp_.x = cvt_pk_bf16(xpre.x, xpre.y);                                  \
            pp_.y = cvt_pk_bf16(xpre.z, xpre.w);                                  \
            *(uint2*)&xb[g][(t) & 1][prow * BS + pcol] = pp_;                     \
            if (gt < 16) abuf[g][((t) + 1) & 1][gt] = apre;                       \
        }                                                                         \
    }

    // ---------- B head-start: H1(0) ----------
    if (g) { H1(0, pg0A, pg1A, pg0B, pg1B, pcB) }
    barrier_lds();

    // ---------- time loop: 4 phase-shifted intervals per 2 steps ----------
    for (int t = 0; t < Tn; t += 2) {
        if (g == 0) { H1(t,     pg0A, pg1A, pg0B, pg1B, pcB) } else { H2(t,     pcA) }
        barrier_lds();
        if (g == 0) { H2(t,     pcA)                         } else { H1(t + 1, pg0B, pg1B, pg0A, pg1A, pcA) }
        barrier_lds();
        if (g == 0) { H1(t + 1, pg0B, pg1B, pg0A, pg1A, pcA) } else { H2(t + 1, pcB) }
        barrier_lds();
        if (g == 0) { H2(t + 1, pcB)                         } else { H1(t + 2, pg0A, pg1A, pg0B, pg1B, pcB) }
        barrier_lds();
    }
#undef H1
#undef H2
}

extern "C" void kernel_launch(void* const* d_in, const int* in_sizes, int n_in,
                              void* d_out, int out_size, void* d_ws, size_t ws_size,
                              hipStream_t stream) {
    (void)in_sizes; (void)n_in; (void)d_ws; (void)ws_size; (void)out_size;
    const float* X   = (const float*)d_in[0];
    const float* ATT = (const float*)d_in[1];
    const float* GK  = (const float*)d_in[2];
    const float* GB  = (const float*)d_in[3];
    const float* CK  = (const float*)d_in[4];
    const float* CB  = (const float*)d_in[5];
    const int*   SL  = (const int*)d_in[6];
    float* OUT = (float*)d_out;

    augru_kernel<<<dim3(Bn / 32), dim3(1024), 0, stream>>>(X, ATT, GK, GB, CK, CB, SL, OUT);
}

// Round 15
// 4102.698 us; speedup vs baseline: 1.0022x; 1.0022x over previous
//
#include <hip/hip_runtime.h>
#include <hip/hip_bf16.h>

// AUGRU dynamic RNN: B=1024, T=512, D=128.
// Round-15 = Round-14 with ONE change: __launch_bounds__(1024, 1).
// Empirical hipcc semantics (4 data points R0/R7/R9/R11/R14): the 2nd
// launch_bounds arg acts as MIN BLOCKS PER CU. (1024,4)/(1024) assumed 2
// blocks -> 8 waves/SIMD -> 64-VGPR cap -> spills (R11/R14's 2.6-4.1ms).
// (1024,1) -> 16 waves/CU -> 4/SIMD -> 128-VGPR cap; per-wave state needs
// 112 -> fits, no spill. This finally runs the TLP=4 test.
// Structure (from R14): 32 blocks x 1024 threads; waves 0-7 = batch group A
// (16 rows), waves 8-15 = group B. Group B half a step behind: each barrier
// interval = {A's H1: gate MFMAs + x-partials + act} || {B's H2: cand MFMA
// + update + stage} -> heterogeneous phases co-resident per SIMD.
// Per-wave stream/math/LDS pattern byte-identical to R9 (525.8us best).

#define Bn 1024
#define Tn 512
#define Dn 128

typedef __attribute__((ext_vector_type(8))) short short8;   // 8 bf16 (4 VGPR)
typedef __attribute__((ext_vector_type(4))) float f32x4;

#define BS 136   // bf16 LDS row stride (shorts): 272 B = 17*16B

#define NL2E  (-1.4426950408889634f)   // -log2(e)
#define N2L2E (-2.8853900817779268f)   // -2*log2(e)

__device__ __forceinline__ short f2bf(float f) {            // cold paths only
    __hip_bfloat16 h = __float2bfloat16(f);   // RNE
    return __builtin_bit_cast(short, h);
}
__device__ __forceinline__ unsigned cvt_pk_bf16(float a, float b) {
    unsigned r;
    asm("v_cvt_pk_bf16_f32 %0, %1, %2" : "=v"(r) : "v"(a), "v"(b));
    return r;
}
// LDS-only barrier: order LDS ops across waves WITHOUT draining vmcnt.
__device__ __forceinline__ void barrier_lds() {
    __builtin_amdgcn_sched_barrier(0);
    asm volatile("s_waitcnt lgkmcnt(0)" ::: "memory");
    __builtin_amdgcn_s_barrier();
    __builtin_amdgcn_sched_barrier(0);
}

#define MFMA_(a, b, c) __builtin_amdgcn_mfma_f32_16x16x32_bf16((a), (b), (c), 0, 0, 0)

__launch_bounds__(1024, 1)
__global__ void augru_kernel(const float* __restrict__ X,    // [B,T,D]
                             const float* __restrict__ ATT,  // [B,T,1]
                             const float* __restrict__ GK,   // [256,256]
                             const float* __restrict__ GB,   // [256]
                             const float* __restrict__ CK,   // [256,128]
                             const float* __restrict__ CB,   // [128]
                             const int*   __restrict__ SL,   // [B,1]
                             float* __restrict__ OUT) {      // [B,T,D]
    __shared__ short hb [2][16 * BS];      // [group] h bf16 mirror
    __shared__ short rhb[2][16 * BS];      // [group] r*h bf16
    __shared__ short xb [2][2][16 * BS];   // [group][slot]; slot s&1 = x(s)
    __shared__ float abuf[2][2][16];       // [group][slot] raw a
    __shared__ int   lenbuf[2][16];

    const int tid  = threadIdx.x;
    const int g    = tid >> 9;          // group 0 (A) / 1 (B)
    const int gt   = tid & 511;         // id within group
    const int wid  = gt >> 6;           // 0..7 column-wave in group
    const int lane = tid & 63;
    const int lm   = lane & 15;
    const int q    = lane >> 4;
    const int b0   = blockIdx.x * 32 + 16 * g;
    const int ccol = 16 * wid + lm;     // wave's owned column

    // ---------- preload weight B-frags (B[k][n]: n=lane&15, k=q*8+j) ----------
    short8 fgx0[4], fgx1[4], fgh0[4], fgh1[4], fcx[4], fch[4];
#pragma unroll
    for (int ks = 0; ks < 4; ++ks) {
        short8 v0, v1, v2, v3, v4, v5;
#pragma unroll
        for (int j = 0; j < 8; ++j) {
            const int k = ks * 32 + q * 8 + j;
            v0[j] = f2bf(GK[k * 256 + ccol]);               // x-part, r col
            v1[j] = f2bf(GK[k * 256 + 128 + ccol]);         // x-part, u col
            v2[j] = f2bf(GK[(128 + k) * 256 + ccol]);       // h-part, r col
            v3[j] = f2bf(GK[(128 + k) * 256 + 128 + ccol]); // h-part, u col
            v4[j] = f2bf(CK[k * 128 + ccol]);               // cand x-part
            v5[j] = f2bf(CK[(128 + k) * 128 + ccol]);       // cand rh-part
        }
        fgx0[ks] = v0; fgx1[ks] = v1; fgh0[ks] = v2; fgh1[ks] = v3;
        fcx[ks] = v4;  fch[ks] = v5;
    }
    const float pb0 = GB[ccol]       * NL2E;
    const float pb1 = GB[128 + ccol] * NL2E;
    const float cbp = CB[ccol]       * N2L2E;

    // ---------- init LDS (each group its own arrays) ----------
    for (int i = gt; i < 16 * BS; i += 512) hb[g][i] = 0;
    if (gt < 16) {
        lenbuf[g][gt]  = SL[b0 + gt];
        abuf[g][0][gt] = ATT[(size_t)(b0 + gt) * Tn];
    }
    const int prow = gt >> 5;             // x staging: row 0..15
    const int pcol = (gt & 31) * 4;       // 4 consecutive floats
    {   // stage x(0) into xb[g][0]
        float4 v = *(const float4*)(X + ((size_t)(b0 + prow) * Tn + 0) * Dn + pcol);
        uint2 pp; pp.x = cvt_pk_bf16(v.x, v.y); pp.y = cvt_pk_bf16(v.z, v.w);
        *(uint2*)&xb[g][0][prow * BS + pcol] = pp;
    }
    __syncthreads();

    int len_i[4];
    float h_reg[4] = {0.f, 0.f, 0.f, 0.f};   // master h: rows q*4+i, col ccol
#pragma unroll
    for (int i = 0; i < 4; ++i) len_i[i] = lenbuf[g][q * 4 + i];

    // ---------- prologue: x-partials (set A) for step 0; stage x(1) ----------
    f32x4 pg0A = {0,0,0,0}, pg1A = {0,0,0,0}, pcA = {0,0,0,0};
    f32x4 pg0B, pg1B, pcB;
    {
        short8 ax0[4];
#pragma unroll
        for (int ks = 0; ks < 4; ++ks)
            ax0[ks] = *(const short8*)&xb[g][0][lm * BS + ks * 32 + q * 8];
#pragma unroll
        for (int ks = 0; ks < 4; ++ks) {
            pg0A = MFMA_(ax0[ks], fgx0[ks], pg0A);
            pg1A = MFMA_(ax0[ks], fgx1[ks], pg1A);
            pcA  = MFMA_(ax0[ks], fcx[ks],  pcA);
        }
        float4 v = *(const float4*)(X + ((size_t)(b0 + prow) * Tn + 1) * Dn + pcol);
        uint2 pp; pp.x = cvt_pk_bf16(v.x, v.y); pp.y = cvt_pk_bf16(v.z, v.w);
        *(uint2*)&xb[g][1][prow * BS + pcol] = pp;
    }
    __syncthreads();

    // state carried across barriers (per wave)
    float4 xpre; float apre; float up[4];

    // H1(t): gate h-MFMAs + x-partial MFMAs + act + rhb write.
#define H1(t, PIN0, PIN1, POUT0, POUT1, POUTC)                                    \
    {                                                                             \
        const int tp1 = ((t) + 1 < Tn) ? (t) + 1 : Tn - 1;                        \
        const int tp2 = ((t) + 2 < Tn) ? (t) + 2 : Tn - 1;                        \
        xpre = *(const float4*)(X + ((size_t)(b0 + prow) * Tn + tp2) * Dn + pcol); \
        apre = (gt < 16) ? ATT[(size_t)(b0 + gt) * Tn + tp1] : 0.0f;              \
        short8 axn[4], ah[4];                                                     \
        _Pragma("unroll")                                                         \
        for (int ks = 0; ks < 4; ++ks) {                                          \
            axn[ks] = *(const short8*)&xb[g][((t) + 1) & 1][lm * BS + ks * 32 + q * 8]; \
            ah[ks]  = *(const short8*)&hb[g][lm * BS + ks * 32 + q * 8];          \
        }                                                                         \
        f32x4 g0 = PIN0, g1 = PIN1;                                               \
        f32x4 n0 = {0,0,0,0}, n1 = {0,0,0,0}, n2 = {0,0,0,0};                     \
        _Pragma("unroll")                                                         \
        for (int ks = 0; ks < 4; ++ks) {                                          \
            g0 = MFMA_(ah[ks], fgh0[ks], g0);                                     \
            g1 = MFMA_(ah[ks], fgh1[ks], g1);                                     \
        }                                                                         \
        _Pragma("unroll")                                                         \
        for (int ks = 0; ks < 4; ++ks) {                                          \
            n0 = MFMA_(axn[ks], fgx0[ks], n0);                                    \
            n1 = MFMA_(axn[ks], fgx1[ks], n1);                                    \
            n2 = MFMA_(axn[ks], fcx[ks],  n2);                                    \
        }                                                                         \
        float am[4], rhv[4];                                                      \
        _Pragma("unroll")                                                         \
        for (int i = 0; i < 4; ++i) am[i] = 1.0f - abuf[g][(t) & 1][q * 4 + i];   \
        _Pragma("unroll")                                                         \
        for (int i = 0; i < 4; ++i) {                                             \
            const float e0 = __builtin_amdgcn_exp2f(fmaf(g0[i], NL2E, pb0));      \
            rhv[i] = __builtin_amdgcn_rcpf(1.0f + e0) * h_reg[i];                 \
            const float e1 = __builtin_amdgcn_exp2f(fmaf(g1[i], NL2E, pb1));      \
            up[i] = am[i] * __builtin_amdgcn_rcpf(1.0f + e1);                     \
        }                                                                         \
        {                                                                         \
            const unsigned pA_ = cvt_pk_bf16(rhv[0], rhv[1]);                     \
            const unsigned pB_ = cvt_pk_bf16(rhv[2], rhv[3]);                     \
            rhb[g][(q * 4 + 0) * BS + ccol] = (short)pA_;                         \
            rhb[g][(q * 4 + 1) * BS + ccol] = (short)(pA_ >> 16);                 \
            rhb[g][(q * 4 + 2) * BS + ccol] = (short)pB_;                         \
            rhb[g][(q * 4 + 3) * BS + ccol] = (short)(pB_ >> 16);                 \
        }                                                                         \
        POUT0 = n0; POUT1 = n1; POUTC = n2;                                       \
    }

    // H2(t): cand MFMA chain + h update + OUT + hb write + stage x/a.
#define H2(t, PINC)                                                               \
    {                                                                             \
        short8 arh[4];                                                            \
        _Pragma("unroll")                                                         \
        for (int ks = 0; ks < 4; ++ks)                                            \
            arh[ks] = *(const short8*)&rhb[g][lm * BS + ks * 32 + q * 8];         \
        f32x4 cc = PINC;                                                          \
        _Pragma("unroll")                                                         \
        for (int ks = 0; ks < 4; ++ks)                                            \
            cc = MFMA_(arh[ks], fch[ks], cc);                                     \
        float hxv[4];                                                             \
        _Pragma("unroll")                                                         \
        for (int i = 0; i < 4; ++i) {                                             \
            const int row = q * 4 + i;                                            \
            const float e  = __builtin_amdgcn_exp2f(fmaf(cc[i], N2L2E, cbp));     \
            const float cv = fmaf(2.0f, __builtin_amdgcn_rcpf(1.0f + e), -1.0f);  \
            const float hn = fmaf(up[i], h_reg[i] - cv, cv);                      \
            const bool valid = ((t) < len_i[i]);                                  \
            const float hnext = valid ? hn : h_reg[i];                            \
            OUT[((size_t)(b0 + row) * Tn + (t)) * Dn + ccol] = valid ? hn : 0.0f; \
            h_reg[i] = hnext;                                                     \
            hxv[i] = hnext;                                                       \
        }                                                                         \
        {                                                                         \
            const unsigned pA_ = cvt_pk_bf16(hxv[0], hxv[1]);                     \
            const unsigned pB_ = cvt_pk_bf16(hxv[2], hxv[3]);                     \
            hb[g][(q * 4 + 0) * BS + ccol] = (short)pA_;                          \
            hb[g][(q * 4 + 1) * BS + ccol] = (short)(pA_ >> 16);                  \
            hb[g][(q * 4 + 2) * BS + ccol] = (short)pB_;                          \
            hb[g][(q * 4 + 3) * BS + ccol] = (short)(pB_ >> 16);                  \
        }                                                                         \
        {                                                                         \
            uint2 pp_;                                                            \
            pp_.x = cvt_pk_bf16(xpre.x, xpre.y);                                  \
            pp_.y = cvt_pk_bf16(xpre.z, xpre.w);                                  \
            *(uint2*)&xb[g][(t) & 1][prow * BS + pcol] = pp_;                     \
            if (gt < 16) abuf[g][((t) + 1) & 1][gt] = apre;                       \
        }                                                                         \
    }

    // ---------- B head-start: H1(0) ----------
    if (g) { H1(0, pg0A, pg1A, pg0B, pg1B, pcB) }
    barrier_lds();

    // ---------- time loop: 4 phase-shifted intervals per 2 steps ----------
    for (int t = 0; t < Tn; t += 2) {
        if (g == 0) { H1(t,     pg0A, pg1A, pg0B, pg1B, pcB) } else { H2(t,     pcA) }
        barrier_lds();
        if (g == 0) { H2(t,     pcA)                         } else { H1(t + 1, pg0B, pg1B, pg0A, pg1A, pcA) }
        barrier_lds();
        if (g == 0) { H1(t + 1, pg0B, pg1B, pg0A, pg1A, pcA) } else { H2(t + 1, pcB) }
        barrier_lds();
        if (g == 0) { H2(t + 1, pcB)                         } else { H1(t + 2, pg0A, pg1A, pg0B, pg1B, pcB) }
        barrier_lds();
    }
#undef H1
#undef H2
}

extern "C" void kernel_launch(void* const* d_in, const int* in_sizes, int n_in,
                              void* d_out, int out_size, void* d_ws, size_t ws_size,
                              hipStream_t stream) {
    (void)in_sizes; (void)n_in; (void)d_ws; (void)ws_size; (void)out_size;
    const float* X   = (const float*)d_in[0];
    const float* ATT = (const float*)d_in[1];
    const float* GK  = (const float*)d_in[2];
    const float* GB  = (const float*)d_in[3];
    const float* CK  = (const float*)d_in[4];
    const float* CB  = (const float*)d_in[5];
    const int*   SL  = (const int*)d_in[6];
    float* OUT = (float*)d_out;

    augru_kernel<<<dim3(Bn / 32), dim3(1024), 0, stream>>>(X, ATT, GK, GB, CK, CB, SL, OUT);
}

// Round 16
// 527.311 us; speedup vs baseline: 7.7973x; 7.7804x over previous
//
#include <hip/hip_runtime.h>
#include <hip/hip_bf16.h>

// AUGRU dynamic RNN: B=1024, T=512, D=128.
// FINAL = Round-9 verbatim (session best, 525.8us; verified). Ladder:
// 630.8 -> 614.7 (R5: cross-step pipelined x-partial MFMAs) -> 587.6
// (R6: v_cvt_pk_bf16_f32 + biases folded into exp2 args) -> 525.8
// (R9: column-aligned gate mapping deletes hf/ub LDS arrays; master h and
// u' live in registers).
// Structure: 64 blocks x 512 threads (8 waves, TLP=2/SIMD); block owns 16
// batch rows for all T steps. Weights as bf16 MFMA B-frags in registers.
// Per step: P1 gate h-MFMAs (4-deep, on saved x-partials) + next-step
// x-partial MFMAs (free-floating) + wave-uniform act; barrier; P2 cand
// rh-MFMAs + register h-update + OUT store + x/a stage; barrier.
// lgkm-only barriers (vmcnt never drained in-loop).
// Structural floor analysis (R10-R15): LDS pipe ~79% of the 2465-cyc step;
// h/rh/x A-frag broadcasts are irreducible cross-wave communication; TLP>2
// unreachable (1024-thread blocks allocate 64 VGPR on this toolchain; state
// needs 112); all overlap/rebalance attempts measured negative.

#define Bn 1024
#define Tn 512
#define Dn 128

typedef __attribute__((ext_vector_type(8))) short short8;   // 8 bf16 (4 VGPR)
typedef __attribute__((ext_vector_type(4))) float f32x4;

#define BS 136   // bf16 LDS row stride (shorts): 272 B = 17*16B

#define NL2E  (-1.4426950408889634f)   // -log2(e)
#define N2L2E (-2.8853900817779268f)   // -2*log2(e)

__device__ __forceinline__ short f2bf(float f) {            // cold paths only
    __hip_bfloat16 h = __float2bfloat16(f);   // RNE
    return __builtin_bit_cast(short, h);
}
__device__ __forceinline__ unsigned cvt_pk_bf16(float a, float b) {
    unsigned r;
    asm("v_cvt_pk_bf16_f32 %0, %1, %2" : "=v"(r) : "v"(a), "v"(b));
    return r;
}
// LDS-only barrier: order LDS ops across waves WITHOUT draining vmcnt.
__device__ __forceinline__ void barrier_lds() {
    __builtin_amdgcn_sched_barrier(0);
    asm volatile("s_waitcnt lgkmcnt(0)" ::: "memory");
    __builtin_amdgcn_s_barrier();
    __builtin_amdgcn_sched_barrier(0);
}

#define MFMA_(a, b, c) __builtin_amdgcn_mfma_f32_16x16x32_bf16((a), (b), (c), 0, 0, 0)

__launch_bounds__(512, 1)
__global__ void augru_kernel(const float* __restrict__ X,    // [B,T,D]
                             const float* __restrict__ ATT,  // [B,T,1]
                             const float* __restrict__ GK,   // [256,256]
                             const float* __restrict__ GB,   // [256]
                             const float* __restrict__ CK,   // [256,128]
                             const float* __restrict__ CB,   // [128]
                             const int*   __restrict__ SL,   // [B,1]
                             float* __restrict__ OUT) {      // [B,T,D]
    __shared__ short hb [16 * BS];      // h  (bf16 mirror, A-frag source)
    __shared__ short rhb[16 * BS];      // r*h (bf16, A-frag source)
    __shared__ short xb [2][16 * BS];   // x tile; slot s&1 holds x(s)
    __shared__ float abuf[2][16];
    __shared__ int   lenbuf[16];

    const int tid  = threadIdx.x;
    const int wid  = tid >> 6;          // 0..7
    const int lane = tid & 63;
    const int lm   = lane & 15;
    const int q    = lane >> 4;
    const int b0   = blockIdx.x * 16;
    const int ccol = 16 * wid + lm;     // wave's owned column (r / u-128 / cand / h)

    // ---------- preload weight B-frags (B[k][n]: n=lane&15, k=q*8+j) ----------
    // gate group 0 -> col ccol (r); gate group 1 -> col 128+ccol (u).
    short8 fgx0[4], fgx1[4], fgh0[4], fgh1[4], fcx[4], fch[4];
#pragma unroll
    for (int ks = 0; ks < 4; ++ks) {
        short8 v0, v1, v2, v3, v4, v5;
#pragma unroll
        for (int j = 0; j < 8; ++j) {
            const int k = ks * 32 + q * 8 + j;
            v0[j] = f2bf(GK[k * 256 + ccol]);               // x-part, r col
            v1[j] = f2bf(GK[k * 256 + 128 + ccol]);         // x-part, u col
            v2[j] = f2bf(GK[(128 + k) * 256 + ccol]);       // h-part, r col
            v3[j] = f2bf(GK[(128 + k) * 256 + 128 + ccol]); // h-part, u col
            v4[j] = f2bf(CK[k * 128 + ccol]);               // cand x-part
            v5[j] = f2bf(CK[(128 + k) * 128 + ccol]);       // cand rh-part
        }
        fgx0[ks] = v0; fgx1[ks] = v1; fgh0[ks] = v2; fgh1[ks] = v3;
        fcx[ks] = v4;  fch[ks] = v5;
    }
    const float pb0 = GB[ccol]       * NL2E;
    const float pb1 = GB[128 + ccol] * NL2E;
    const float cbp = CB[ccol]       * N2L2E;

    // ---------- init LDS ----------
    for (int i = tid; i < 16 * BS; i += 512) hb[i] = 0;
    if (tid < 16) {
        lenbuf[tid]  = SL[b0 + tid];
        abuf[0][tid] = ATT[(size_t)(b0 + tid) * Tn];
    }
    const int prow = tid >> 5;            // x staging: row 0..15
    const int pcol = (tid & 31) * 4;      // 4 consecutive floats
    {   // stage x(0) into xb[0]
        float4 v = *(const float4*)(X + ((size_t)(b0 + prow) * Tn + 0) * Dn + pcol);
        uint2 pp; pp.x = cvt_pk_bf16(v.x, v.y); pp.y = cvt_pk_bf16(v.z, v.w);
        *(uint2*)&xb[0][prow * BS + pcol] = pp;
    }
    __syncthreads();

    int len_i[4];
    float h_reg[4] = {0.f, 0.f, 0.f, 0.f};   // master h: rows q*4+i, col ccol
#pragma unroll
    for (int i = 0; i < 4; ++i) len_i[i] = lenbuf[q * 4 + i];

    // ---------- prologue: x-partials for t=0; stage x(1) ----------
    f32x4 gxA0 = {0,0,0,0}, gxA1 = {0,0,0,0}, cxA = {0,0,0,0};
    f32x4 gxB0, gxB1, cxB;
    {
        short8 ax0[4];
#pragma unroll
        for (int ks = 0; ks < 4; ++ks)
            ax0[ks] = *(const short8*)&xb[0][lm * BS + ks * 32 + q * 8];
#pragma unroll
        for (int ks = 0; ks < 4; ++ks) {
            gxA0 = MFMA_(ax0[ks], fgx0[ks], gxA0);
            gxA1 = MFMA_(ax0[ks], fgx1[ks], gxA1);
            cxA  = MFMA_(ax0[ks], fcx[ks],  cxA);
        }
        float4 v = *(const float4*)(X + ((size_t)(b0 + prow) * Tn + 1) * Dn + pcol);
        uint2 pp; pp.x = cvt_pk_bf16(v.x, v.y); pp.y = cvt_pk_bf16(v.z, v.w);
        *(uint2*)&xb[1][prow * BS + pcol] = pp;
    }
    __syncthreads();

#define STEP_BODY(t, GIN0, GIN1, CIN, GOUT0, GOUT1, COUT)                         \
    {                                                                             \
        const int cur = (t) & 1, nxt = cur ^ 1;                                   \
        const int tp1 = ((t) + 1 < Tn) ? (t) + 1 : Tn - 1;                        \
        const int tp2 = ((t) + 2 < Tn) ? (t) + 2 : Tn - 1;                        \
        float4 xpre = *(const float4*)(X + ((size_t)(b0 + prow) * Tn + tp2) * Dn + pcol); \
        float  apre = (tid < 16) ? ATT[(size_t)(b0 + tid) * Tn + tp1] : 0.0f;     \
        /* A-frags: h(t) from hb, x(t+1) from xb[nxt] */                          \
        short8 axn[4], ah[4];                                                     \
        _Pragma("unroll")                                                         \
        for (int ks = 0; ks < 4; ++ks) {                                          \
            axn[ks] = *(const short8*)&xb[nxt][lm * BS + ks * 32 + q * 8];        \
            ah[ks]  = *(const short8*)&hb[lm * BS + ks * 32 + q * 8];             \
        }                                                                         \
        /* P1: gate = saved x-partial + h-part (4-deep); next x-partials float */ \
        f32x4 g0 = GIN0, g1 = GIN1;                                               \
        f32x4 n0 = {0,0,0,0}, n1 = {0,0,0,0}, n2 = {0,0,0,0};                     \
        _Pragma("unroll")                                                         \
        for (int ks = 0; ks < 4; ++ks) {                                          \
            g0 = MFMA_(ah[ks], fgh0[ks], g0);                                     \
            g1 = MFMA_(ah[ks], fgh1[ks], g1);                                     \
        }                                                                         \
        _Pragma("unroll")                                                         \
        for (int ks = 0; ks < 4; ++ks) {                                          \
            n0 = MFMA_(axn[ks], fgx0[ks], n0);                                    \
            n1 = MFMA_(axn[ks], fgx1[ks], n1);                                    \
            n2 = MFMA_(axn[ks], fcx[ks],  n2);                                    \
        }                                                                         \
        /* activations: wave-uniform; r,u for col ccol in the owning lane */      \
        float am[4], up[4], rhv[4];                                               \
        _Pragma("unroll")                                                         \
        for (int i = 0; i < 4; ++i) am[i] = 1.0f - abuf[cur][q * 4 + i];          \
        _Pragma("unroll")                                                         \
        for (int i = 0; i < 4; ++i) {                                             \
            const float e0 = __builtin_amdgcn_exp2f(fmaf(g0[i], NL2E, pb0));      \
            rhv[i] = __builtin_amdgcn_rcpf(1.0f + e0) * h_reg[i];                 \
            const float e1 = __builtin_amdgcn_exp2f(fmaf(g1[i], NL2E, pb1));      \
            up[i] = am[i] * __builtin_amdgcn_rcpf(1.0f + e1);                     \
        }                                                                         \
        {                                                                         \
            const unsigned pA_ = cvt_pk_bf16(rhv[0], rhv[1]);                     \
            const unsigned pB_ = cvt_pk_bf16(rhv[2], rhv[3]);                     \
            rhb[(q * 4 + 0) * BS + ccol] = (short)pA_;                            \
            rhb[(q * 4 + 1) * BS + ccol] = (short)(pA_ >> 16);                    \
            rhb[(q * 4 + 2) * BS + ccol] = (short)pB_;                            \
            rhb[(q * 4 + 3) * BS + ccol] = (short)(pB_ >> 16);                    \
        }                                                                         \
        barrier_lds();                                                            \
        /* P2: cand = saved x-partial + rh-part (4-deep) */                       \
        f32x4 cc = CIN;                                                           \
        _Pragma("unroll")                                                         \
        for (int ks = 0; ks < 4; ++ks) {                                          \
            short8 arh = *(const short8*)&rhb[lm * BS + ks * 32 + q * 8];         \
            cc = MFMA_(arh, fch[ks], cc);                                         \
        }                                                                         \
        /* h update + output (all state register-resident) */                     \
        float hxv[4];                                                             \
        _Pragma("unroll")                                                         \
        for (int i = 0; i < 4; ++i) {                                             \
            const int row = q * 4 + i;                                            \
            const float e  = __builtin_amdgcn_exp2f(fmaf(cc[i], N2L2E, cbp));     \
            const float cv = fmaf(2.0f, __builtin_amdgcn_rcpf(1.0f + e), -1.0f);  \
            const float hn = fmaf(up[i], h_reg[i] - cv, cv);                      \
            const bool valid = ((t) < len_i[i]);                                  \
            const float hnext = valid ? hn : h_reg[i];                            \
            OUT[((size_t)(b0 + row) * Tn + (t)) * Dn + ccol] = valid ? hn : 0.0f; \
            h_reg[i] = hnext;                                                     \
            hxv[i] = hnext;                                                       \
        }                                                                         \
        {                                                                         \
            const unsigned pA_ = cvt_pk_bf16(hxv[0], hxv[1]);                     \
            const unsigned pB_ = cvt_pk_bf16(hxv[2], hxv[3]);                     \
            hb[(q * 4 + 0) * BS + ccol] = (short)pA_;                             \
            hb[(q * 4 + 1) * BS + ccol] = (short)(pA_ >> 16);                     \
            hb[(q * 4 + 2) * BS + ccol] = (short)pB_;                             \
            hb[(q * 4 + 3) * BS + ccol] = (short)(pB_ >> 16);                     \
        }                                                                         \
        /* stage x(t+2) into xb[cur]; a(t+1) into abuf[nxt] */                    \
        {                                                                         \
            uint2 pp_;                                                            \
            pp_.x = cvt_pk_bf16(xpre.x, xpre.y);                                  \
            pp_.y = cvt_pk_bf16(xpre.z, xpre.w);                                  \
            *(uint2*)&xb[cur][prow * BS + pcol] = pp_;                            \
            if (tid < 16) abuf[nxt][tid] = apre;                                  \
        }                                                                         \
        barrier_lds();                                                            \
        GOUT0 = n0; GOUT1 = n1; COUT = n2;                                        \
    }

    // ---------- time loop (unrolled x2: static A/B partial-sum sets) ----------
    for (int t = 0; t < Tn; t += 2) {
        STEP_BODY(t,     gxA0, gxA1, cxA, gxB0, gxB1, cxB)
        STEP_BODY(t + 1, gxB0, gxB1, cxB, gxA0, gxA1, cxA)
    }
#undef STEP_BODY
}

extern "C" void kernel_launch(void* const* d_in, const int* in_sizes, int n_in,
                              void* d_out, int out_size, void* d_ws, size_t ws_size,
                              hipStream_t stream) {
    (void)in_sizes; (void)n_in; (void)d_ws; (void)ws_size; (void)out_size;
    const float* X   = (const float*)d_in[0];
    const float* ATT = (const float*)d_in[1];
    const float* GK  = (const float*)d_in[2];
    const float* GB  = (const float*)d_in[3];
    const float* CK  = (const float*)d_in[4];
    const float* CB  = (const float*)d_in[5];
    const int*   SL  = (const int*)d_in[6];
    float* OUT = (float*)d_out;

    augru_kernel<<<dim3(Bn / 16), dim3(512), 0, stream>>>(X, ATT, GK, GB, CK, CB, SL, OUT);
}